// Round 1
// baseline (74.719 us; speedup 1.0000x reference)
//
#include <hip/hip_runtime.h>

#define BB 4
#define CIN 3
#define HH 512
#define WW 512
#define KH 3
#define KW 3
#define KK 9
#define COUT 3
#define HO 510
#define WO 510

__global__ __launch_bounds__(256) void deform_fused_kernel(
    const float* __restrict__ x,   // [B, CIN, H, W]
    const float* __restrict__ w1,  // [18, CIN, 3, 3]
    const float* __restrict__ b1,  // [18]
    const float* __restrict__ w2,  // [COUT, CIN, 3, 3]
    const float* __restrict__ b2,  // [COUT]
    float* __restrict__ out)       // [B, COUT, HO, WO]
{
    __shared__ float s_w1[18 * 27];
    __shared__ float s_b1[18];
    __shared__ float s_w2[COUT * CIN * KK];  // 81
    __shared__ float s_b2[COUT];

    for (int t = threadIdx.x; t < 18 * 27; t += blockDim.x) s_w1[t] = w1[t];
    if (threadIdx.x < 18) s_b1[threadIdx.x] = b1[threadIdx.x];
    if (threadIdx.x < COUT * CIN * KK) s_w2[threadIdx.x] = w2[threadIdx.x];
    if (threadIdx.x < COUT) s_b2[threadIdx.x] = b2[threadIdx.x];
    __syncthreads();

    const int idx = blockIdx.x * blockDim.x + threadIdx.x;
    const int total = BB * HO * WO;
    if (idx >= total) return;

    const int j = idx % WO;
    const int tmp = idx / WO;
    const int i = tmp % HO;
    const int b = tmp / HO;

    const float* xb = x + (size_t)b * CIN * HH * WW;

    // Load the 3x3x3 input patch into registers (fully unrolled -> VGPRs).
    float patch[CIN][KH][KW];
#pragma unroll
    for (int c = 0; c < CIN; ++c)
#pragma unroll
        for (int r = 0; r < KH; ++r)
#pragma unroll
            for (int s = 0; s < KW; ++s)
                patch[c][r][s] = xb[c * HH * WW + (i + r) * WW + (j + s)];

    float acc0 = s_b2[0], acc1 = s_b2[1], acc2 = s_b2[2];

#pragma unroll
    for (int k = 0; k < KK; ++k) {
        const int ky = k / 3;
        const int kx = k % 3;

        // conv1 channels 2k (dy) and 2k+1 (dx): dot(patch, w1-row) + bias
        float dy = s_b1[2 * k];
        float dx = s_b1[2 * k + 1];
        const float* wy = &s_w1[(2 * k) * 27];
        const float* wx = &s_w1[(2 * k + 1) * 27];
        int t = 0;
#pragma unroll
        for (int c = 0; c < CIN; ++c)
#pragma unroll
            for (int r = 0; r < KH; ++r)
#pragma unroll
                for (int s = 0; s < KW; ++s, ++t) {
                    const float pv = patch[c][r][s];
                    dy += pv * wy[t];
                    dx += pv * wx[t];
                }

        const float sy = (float)(i + ky) + dy;
        const float sx = (float)(j + kx) + dx;
        const float y0f = floorf(sy);
        const float x0f = floorf(sx);
        const float fy = sy - y0f;
        const float fx = sx - x0f;
        const int y0 = (int)y0f;
        const int x0 = (int)x0f;

        float v0 = 0.f, v1 = 0.f, v2 = 0.f;  // per input channel
#pragma unroll
        for (int cy = 0; cy < 2; ++cy) {
            const int iy = y0 + cy;
            const float wyf = cy ? fy : (1.f - fy);
            const bool vy = (iy >= 0) && (iy < HH);
            const int iyc = iy < 0 ? 0 : (iy > HH - 1 ? HH - 1 : iy);
#pragma unroll
            for (int cx = 0; cx < 2; ++cx) {
                const int ix = x0 + cx;
                const float wxf = cx ? fx : (1.f - fx);
                const bool vx = (ix >= 0) && (ix < WW);
                const int ixc = ix < 0 ? 0 : (ix > WW - 1 ? WW - 1 : ix);
                const float wgt = (vy && vx) ? (wyf * wxf) : 0.f;
                const size_t base = (size_t)iyc * WW + ixc;
                v0 += wgt * xb[0 * HH * WW + base];
                v1 += wgt * xb[1 * HH * WW + base];
                v2 += wgt * xb[2 * HH * WW + base];
            }
        }

        // conv2 accumulate: acc[o] += w2[o][c][k] * val[c]
#pragma unroll
        for (int o = 0; o < COUT; ++o) {
            const float w2o0 = s_w2[(o * CIN + 0) * KK + k];
            const float w2o1 = s_w2[(o * CIN + 1) * KK + k];
            const float w2o2 = s_w2[(o * CIN + 2) * KK + k];
            const float contrib = w2o0 * v0 + w2o1 * v1 + w2o2 * v2;
            if (o == 0) acc0 += contrib;
            else if (o == 1) acc1 += contrib;
            else acc2 += contrib;
        }
    }

    float* ob = out + (size_t)b * COUT * HO * WO + (size_t)i * WO + j;
    ob[0 * HO * WO] = acc0;
    ob[1 * HO * WO] = acc1;
    ob[2 * HO * WO] = acc2;
}

extern "C" void kernel_launch(void* const* d_in, const int* in_sizes, int n_in,
                              void* d_out, int out_size, void* d_ws, size_t ws_size,
                              hipStream_t stream) {
    const float* x  = (const float*)d_in[0];
    const float* w1 = (const float*)d_in[1];
    const float* b1 = (const float*)d_in[2];
    const float* w2 = (const float*)d_in[3];
    const float* b2 = (const float*)d_in[4];
    float* out = (float*)d_out;

    const int total = BB * HO * WO;
    const int block = 256;
    const int grid = (total + block - 1) / block;
    deform_fused_kernel<<<grid, block, 0, stream>>>(x, w1, b1, w2, b2, out);
}